// Round 1
// baseline (1324.447 us; speedup 1.0000x reference)
//
#include <hip/hip_runtime.h>
#include <math.h>

#define B_ 8
#define C_ 128
#define N_ 16384
#define SCALE_ 0.17677669529663687f
#define EPS_ 1e-5f

#define XS_STRIDE 133   // x / ctx tile, pixel-major [32][133]
#define WT_STRIDE 260   // w chunk, c-major [16][260]
#define KV_STRIDE 36    // k/v tiles [128][36]
#define QS_STRIDE 132   // q / y tile [32][132]
#define AS_STRIDE 133   // attn tile [32][133]

// ---------------------------------------------------------------------------
// Kernel 1: k/v GEMM (rows 128..383 of w_qkv) over a 32-pixel chunk,
// exp(k), then atomic accumulation of S[row] = sum_n exp(k) and
// P[dk][dv] = sum_n exp(k_dk)*v_dv  into workspace.
// grid = B_ * 512, block = 256
// ---------------------------------------------------------------------------
__global__ __launch_bounds__(256, 2) void lin_attn_ctx(
    const float* __restrict__ x, const float* __restrict__ wqkv,
    float* __restrict__ Sg, float* __restrict__ Pg)
{
  __shared__ __align__(16) float xs[32 * XS_STRIDE];
  __shared__ __align__(16) float wt[16 * WT_STRIDE];
  __shared__ __align__(16) float ks[128 * KV_STRIDE];
  __shared__ __align__(16) float vs[128 * KV_STRIDE];

  const int t = threadIdx.x;
  const int b = blockIdx.x >> 9;
  const int p0 = (blockIdx.x & 511) << 5;

  // stage x tile [128 c][32 px] -> xs[px][c] (transposed, pixel-major)
  {
    const float* xb = x + ((size_t)b * C_) * N_ + p0;
#pragma unroll
    for (int i = 0; i < 4; ++i) {
      int lin = t + 256 * i;            // 1024 float4s
      int c = lin >> 3;
      int pq = (lin & 7) << 2;
      float4 f = *(const float4*)(xb + (size_t)c * N_ + pq);
      xs[(pq + 0) * XS_STRIDE + c] = f.x;
      xs[(pq + 1) * XS_STRIDE + c] = f.y;
      xs[(pq + 2) * XS_STRIDE + c] = f.z;
      xs[(pq + 3) * XS_STRIDE + c] = f.w;
    }
  }

  const int pg = t & 7;   // pixel group: px = pg*4..pg*4+3
  const int rg = t >> 3;  // row group: rows rg*8..rg*8+7 (256 kv rows)

  float acc[8][4];
#pragma unroll
  for (int i = 0; i < 8; ++i)
#pragma unroll
    for (int j = 0; j < 4; ++j) acc[i][j] = 0.f;

  for (int kc = 0; kc < 8; ++kc) {
    __syncthreads();
    // stage w chunk: rows 128..383, cols kc*16..+15  ->  wt[cc][r]
#pragma unroll
    for (int i = 0; i < 4; ++i) {
      int lin = t + 256 * i;            // 1024 float4s
      int r = lin >> 2;                 // 0..255
      int cq = (lin & 3) << 2;
      float4 f = *(const float4*)(wqkv + (size_t)(128 + r) * C_ + (kc << 4) + cq);
      wt[(cq + 0) * WT_STRIDE + r] = f.x;
      wt[(cq + 1) * WT_STRIDE + r] = f.y;
      wt[(cq + 2) * WT_STRIDE + r] = f.z;
      wt[(cq + 3) * WT_STRIDE + r] = f.w;
    }
    __syncthreads();
#pragma unroll
    for (int c = 0; c < 16; ++c) {
      float4 wa = *(const float4*)&wt[c * WT_STRIDE + rg * 8];
      float4 wb = *(const float4*)&wt[c * WT_STRIDE + rg * 8 + 4];
      int col = (kc << 4) + c;
#pragma unroll
      for (int j = 0; j < 4; ++j) {
        float xv = xs[(pg * 4 + j) * XS_STRIDE + col];
        acc[0][j] += wa.x * xv; acc[1][j] += wa.y * xv;
        acc[2][j] += wa.z * xv; acc[3][j] += wa.w * xv;
        acc[4][j] += wb.x * xv; acc[5][j] += wb.y * xv;
        acc[6][j] += wb.z * xv; acc[7][j] += wb.w * xv;
      }
    }
  }
  __syncthreads();
  // rows 0..127 are k (store exp(k)); rows 128..255 are v (store raw).
  if (rg < 16) {
#pragma unroll
    for (int i = 0; i < 8; ++i) {
      int row = rg * 8 + i;
#pragma unroll
      for (int j = 0; j < 4; ++j)
        ks[row * KV_STRIDE + pg * 4 + j] = expf(acc[i][j]);
    }
  } else {
#pragma unroll
    for (int i = 0; i < 8; ++i) {
      int row = (rg - 16) * 8 + i;
#pragma unroll
      for (int j = 0; j < 4; ++j)
        vs[row * KV_STRIDE + pg * 4 + j] = acc[i][j];
    }
  }
  __syncthreads();
  // S partials: thread -> (row r = t>>1, half = t&1)
  {
    int r = t >> 1, half = t & 1;
    float s = 0.f;
#pragma unroll
    for (int p = 0; p < 16; ++p) s += ks[r * KV_STRIDE + half * 16 + p];
    s += __shfl_xor(s, 1);
    if (half == 0) atomicAdd(&Sg[b * 128 + r], s);
  }
  // P partials: thread -> (h = t>>6, dk = (t>>1)&31, dv half = t&1)
  {
    int h = t >> 6, dk = (t >> 1) & 31, dvh = t & 1;
    float ek[32];
    const float* krow = &ks[(h * 32 + dk) * KV_STRIDE];
#pragma unroll
    for (int q = 0; q < 8; ++q) {
      float4 f = *(const float4*)&krow[q * 4];
      ek[q * 4 + 0] = f.x; ek[q * 4 + 1] = f.y;
      ek[q * 4 + 2] = f.z; ek[q * 4 + 3] = f.w;
    }
#pragma unroll
    for (int u = 0; u < 16; ++u) {
      int dv = dvh * 16 + u;
      const float* vrow = &vs[(h * 32 + dv) * KV_STRIDE];
      float p = 0.f;
#pragma unroll
      for (int q = 0; q < 8; ++q) {
        float4 f = *(const float4*)&vrow[q * 4];
        p += ek[q * 4 + 0] * f.x + ek[q * 4 + 1] * f.y +
             ek[q * 4 + 2] * f.z + ek[q * 4 + 3] * f.w;
      }
      atomicAdd(&Pg[((b * 4 + h) * 32 + dk) * 32 + dv], p);
    }
  }
}

// ---------------------------------------------------------------------------
// Kernel 2: q GEMM (rows 0..127 of w_qkv) -> per-pixel head softmax*scale ->
// attn = ctx^T q -> W_out GEMM + bias -> channel LayerNorm -> out.
// grid = B_ * 512, block = 256
// ---------------------------------------------------------------------------
__global__ __launch_bounds__(256, 2) void lin_attn_out(
    const float* __restrict__ x, const float* __restrict__ wqkv,
    const float* __restrict__ wout, const float* __restrict__ bout,
    const float* __restrict__ alpha, const float* __restrict__ beta,
    const float* __restrict__ Sg, const float* __restrict__ Pg,
    float* __restrict__ out)
{
  __shared__ __align__(16) float xs[32 * XS_STRIDE];  // x tile, later ctx[4][32][32]
  __shared__ __align__(16) float wt[16 * WT_STRIDE];
  __shared__ __align__(16) float qs[32 * QS_STRIDE];  // q tile, later y tile
  __shared__ __align__(16) float as_[32 * AS_STRIDE]; // attn tile
  __shared__ float red_s[256];
  __shared__ float red_q[256];

  const int t = threadIdx.x;
  const int b = blockIdx.x >> 9;
  const int p0 = (blockIdx.x & 511) << 5;

  // stage x tile
  {
    const float* xb = x + ((size_t)b * C_) * N_ + p0;
#pragma unroll
    for (int i = 0; i < 4; ++i) {
      int lin = t + 256 * i;
      int c = lin >> 3;
      int pq = (lin & 7) << 2;
      float4 f = *(const float4*)(xb + (size_t)c * N_ + pq);
      xs[(pq + 0) * XS_STRIDE + c] = f.x;
      xs[(pq + 1) * XS_STRIDE + c] = f.y;
      xs[(pq + 2) * XS_STRIDE + c] = f.z;
      xs[(pq + 3) * XS_STRIDE + c] = f.w;
    }
  }

  const int pg = t & 7;   // px = pg*4..pg*4+3
  const int rg = t >> 3;  // rows rg*4..rg*4+3 (128 rows)

  float acc[4][4];
#pragma unroll
  for (int i = 0; i < 4; ++i)
#pragma unroll
    for (int j = 0; j < 4; ++j) acc[i][j] = 0.f;

  // ---- q GEMM ----
  for (int kc = 0; kc < 8; ++kc) {
    __syncthreads();
#pragma unroll
    for (int i = 0; i < 2; ++i) {
      int lin = t + 256 * i;            // 512 float4s
      int r = lin >> 2;                 // 0..127
      int cq = (lin & 3) << 2;
      float4 f = *(const float4*)(wqkv + (size_t)r * C_ + (kc << 4) + cq);
      wt[(cq + 0) * WT_STRIDE + r] = f.x;
      wt[(cq + 1) * WT_STRIDE + r] = f.y;
      wt[(cq + 2) * WT_STRIDE + r] = f.z;
      wt[(cq + 3) * WT_STRIDE + r] = f.w;
    }
    __syncthreads();
#pragma unroll
    for (int c = 0; c < 16; ++c) {
      float4 wv = *(const float4*)&wt[c * WT_STRIDE + rg * 4];
      int col = (kc << 4) + c;
#pragma unroll
      for (int j = 0; j < 4; ++j) {
        float xv = xs[(pg * 4 + j) * XS_STRIDE + col];
        acc[0][j] += wv.x * xv; acc[1][j] += wv.y * xv;
        acc[2][j] += wv.z * xv; acc[3][j] += wv.w * xv;
      }
    }
  }
  // write q tile (pixel-major)
#pragma unroll
  for (int i = 0; i < 4; ++i)
#pragma unroll
    for (int j = 0; j < 4; ++j)
      qs[(pg * 4 + j) * QS_STRIDE + rg * 4 + i] = acc[i][j];
  __syncthreads();
  // stage normalized context into xs region: ctx = P / (S * n)
#pragma unroll
  for (int i = 0; i < 16; ++i) {
    int lin = t + 256 * i;              // 4096 entries: h*1024 + dk*32 + dv
    xs[lin] = Pg[b * 4096 + lin] / (Sg[b * 128 + (lin >> 5)] * 16384.f);
  }
  __syncthreads();
  // ---- per-pixel head softmax + attn matvec ----
  {
    int px = t & 31, h = (t >> 5) & 3, dvh = t >> 7;
    float qv[32];
#pragma unroll
    for (int q = 0; q < 8; ++q) {
      float4 f = *(const float4*)&qs[px * QS_STRIDE + h * 32 + q * 4];
      qv[q * 4 + 0] = f.x; qv[q * 4 + 1] = f.y;
      qv[q * 4 + 2] = f.z; qv[q * 4 + 3] = f.w;
    }
    float m = qv[0];
#pragma unroll
    for (int j = 1; j < 32; ++j) m = fmaxf(m, qv[j]);
    float s = 0.f;
#pragma unroll
    for (int j = 0; j < 32; ++j) { qv[j] = expf(qv[j] - m); s += qv[j]; }
    float inv = SCALE_ / s;
#pragma unroll
    for (int j = 0; j < 32; ++j) qv[j] *= inv;
    float av[16];
#pragma unroll
    for (int u = 0; u < 16; ++u) av[u] = 0.f;
#pragma unroll
    for (int dk = 0; dk < 32; ++dk) {
      float qk = qv[dk];
      const float* crow = &xs[h * 1024 + dk * 32 + dvh * 16];
#pragma unroll
      for (int u = 0; u < 4; ++u) {
        float4 f = *(const float4*)&crow[u * 4];
        av[u * 4 + 0] += qk * f.x; av[u * 4 + 1] += qk * f.y;
        av[u * 4 + 2] += qk * f.z; av[u * 4 + 3] += qk * f.w;
      }
    }
#pragma unroll
    for (int u = 0; u < 16; ++u)
      as_[px * AS_STRIDE + h * 32 + dvh * 16 + u] = av[u];
  }
  // ---- W_out GEMM ----
#pragma unroll
  for (int i = 0; i < 4; ++i)
#pragma unroll
    for (int j = 0; j < 4; ++j) acc[i][j] = 0.f;
  for (int kc = 0; kc < 8; ++kc) {
    __syncthreads();
#pragma unroll
    for (int i = 0; i < 2; ++i) {
      int lin = t + 256 * i;
      int r = lin >> 2;
      int cq = (lin & 3) << 2;
      float4 f = *(const float4*)(wout + (size_t)r * C_ + (kc << 4) + cq);
      wt[(cq + 0) * WT_STRIDE + r] = f.x;
      wt[(cq + 1) * WT_STRIDE + r] = f.y;
      wt[(cq + 2) * WT_STRIDE + r] = f.z;
      wt[(cq + 3) * WT_STRIDE + r] = f.w;
    }
    __syncthreads();
#pragma unroll
    for (int c = 0; c < 16; ++c) {
      float4 wv = *(const float4*)&wt[c * WT_STRIDE + rg * 4];
      int col = (kc << 4) + c;
#pragma unroll
      for (int j = 0; j < 4; ++j) {
        float xv = as_[(pg * 4 + j) * AS_STRIDE + col];
        acc[0][j] += wv.x * xv; acc[1][j] += wv.y * xv;
        acc[2][j] += wv.z * xv; acc[3][j] += wv.w * xv;
      }
    }
  }
  // bias + write y tile into qs region (q tile is dead)
  {
    float bias[4];
#pragma unroll
    for (int i = 0; i < 4; ++i) bias[i] = bout[rg * 4 + i];
#pragma unroll
    for (int i = 0; i < 4; ++i)
#pragma unroll
      for (int j = 0; j < 4; ++j)
        qs[(pg * 4 + j) * QS_STRIDE + rg * 4 + i] = acc[i][j] + bias[i];
  }
  __syncthreads();
  // ---- LayerNorm over 128 channels per pixel ----
  {
    int px = t & 31, cg = t >> 5;       // cg: 8 groups of 16 channels
    float y[16];
#pragma unroll
    for (int u = 0; u < 4; ++u) {
      float4 f = *(const float4*)&qs[px * QS_STRIDE + cg * 16 + u * 4];
      y[u * 4 + 0] = f.x; y[u * 4 + 1] = f.y;
      y[u * 4 + 2] = f.z; y[u * 4 + 3] = f.w;
    }
    float sm = 0.f, sq = 0.f;
#pragma unroll
    for (int u = 0; u < 16; ++u) { sm += y[u]; sq += y[u] * y[u]; }
    red_s[cg * 32 + px] = sm;
    red_q[cg * 32 + px] = sq;
    __syncthreads();
    float ts = 0.f, tq = 0.f;
#pragma unroll
    for (int g = 0; g < 8; ++g) { ts += red_s[g * 32 + px]; tq += red_q[g * 32 + px]; }
    float mean = ts * (1.f / 128.f);
    float var = tq * (1.f / 128.f) - mean * mean;
    float rstd = 1.f / sqrtf(var + EPS_);
    float* ob = out + ((size_t)b * C_) * N_ + p0 + px;
#pragma unroll
    for (int u = 0; u < 16; ++u) {
      int ch = cg * 16 + u;
      ob[(size_t)ch * N_] = (y[u] - mean) * rstd * alpha[ch] + beta[ch];
    }
  }
}

extern "C" void kernel_launch(void* const* d_in, const int* in_sizes, int n_in,
                              void* d_out, int out_size, void* d_ws, size_t ws_size,
                              hipStream_t stream) {
  const float* x     = (const float*)d_in[0];
  const float* wqkv  = (const float*)d_in[1];
  const float* wout  = (const float*)d_in[2];
  const float* bout  = (const float*)d_in[3];
  const float* alpha = (const float*)d_in[4];
  const float* beta  = (const float*)d_in[5];
  float* outp = (float*)d_out;
  float* Sg = (float*)d_ws;                  // [B][128]
  float* Pg = Sg + B_ * 128;                 // [B][4][32][32]
  hipMemsetAsync(d_ws, 0, (size_t)(B_ * 128 + B_ * 4096) * sizeof(float), stream);
  lin_attn_ctx<<<dim3(B_ * 512), dim3(256), 0, stream>>>(x, wqkv, Sg, Pg);
  lin_attn_out<<<dim3(B_ * 512), dim3(256), 0, stream>>>(x, wqkv, wout, bout,
                                                         alpha, beta, Sg, Pg, outp);
}

// Round 2
// 626.132 us; speedup vs baseline: 2.1153x; 2.1153x over previous
//
#include <hip/hip_runtime.h>
#include <math.h>

#define B_ 8
#define C_ 128
#define N_ 16384
#define SCALE_ 0.17677669529663687f
#define EPS_ 1e-5f

#define XS_STRIDE 133   // x / ctx tile, pixel-major [32][133]
#define WT_STRIDE 260   // w chunk, c-major [16][260]
#define KV_STRIDE 36    // k/v tiles [128][36]
#define QS_STRIDE 132   // q / y tile [32][132]
#define AS_STRIDE 133   // attn tile [32][133]

// ---------------------------------------------------------------------------
// Kernel 1: k/v GEMM (rows 128..383 of w_qkv) over 4 chunks of 32 pixels
// (128 px per block), exp(k), accumulate S/P partials in REGISTERS across
// chunks, then one atomicAdd per value into one of 32 slots per batch
// (4 writers per address -> no cross-XCD ping-pong).
// grid = B_ * 128, block = 256
// ---------------------------------------------------------------------------
__global__ __launch_bounds__(256, 2) void lin_attn_ctx(
    const float* __restrict__ x, const float* __restrict__ wqkv,
    float* __restrict__ Sp, float* __restrict__ Pp)
{
  __shared__ __align__(16) float xs[32 * XS_STRIDE];
  __shared__ __align__(16) float wt[16 * WT_STRIDE];
  __shared__ __align__(16) float ks[128 * KV_STRIDE];
  __shared__ __align__(16) float vs[128 * KV_STRIDE];

  const int t = threadIdx.x;
  const int b = blockIdx.x >> 7;
  const int pbase = (blockIdx.x & 127) << 7;
  const int slot = blockIdx.x & 31;

  const int pg = t & 7;   // pixel group: px = pg*4..pg*4+3
  const int rg = t >> 3;  // row group: rows rg*8..rg*8+7 (256 kv rows)

  float pacc[16];
#pragma unroll
  for (int u = 0; u < 16; ++u) pacc[u] = 0.f;
  float sacc = 0.f;

  for (int c4 = 0; c4 < 4; ++c4) {
    const int p0 = pbase + (c4 << 5);
    __syncthreads();
    // stage x tile [128 c][32 px] -> xs[px][c] (transposed, pixel-major)
    {
      const float* xb = x + ((size_t)b * C_) * N_ + p0;
#pragma unroll
      for (int i = 0; i < 4; ++i) {
        int lin = t + 256 * i;            // 1024 float4s
        int c = lin >> 3;
        int pq = (lin & 7) << 2;
        float4 f = *(const float4*)(xb + (size_t)c * N_ + pq);
        xs[(pq + 0) * XS_STRIDE + c] = f.x;
        xs[(pq + 1) * XS_STRIDE + c] = f.y;
        xs[(pq + 2) * XS_STRIDE + c] = f.z;
        xs[(pq + 3) * XS_STRIDE + c] = f.w;
      }
    }

    float acc[8][4];
#pragma unroll
    for (int i = 0; i < 8; ++i)
#pragma unroll
      for (int j = 0; j < 4; ++j) acc[i][j] = 0.f;

    for (int kc = 0; kc < 8; ++kc) {
      __syncthreads();
      // stage w chunk: rows 128..383, cols kc*16..+15  ->  wt[cc][r]
#pragma unroll
      for (int i = 0; i < 4; ++i) {
        int lin = t + 256 * i;            // 1024 float4s
        int r = lin >> 2;                 // 0..255
        int cq = (lin & 3) << 2;
        float4 f = *(const float4*)(wqkv + (size_t)(128 + r) * C_ + (kc << 4) + cq);
        wt[(cq + 0) * WT_STRIDE + r] = f.x;
        wt[(cq + 1) * WT_STRIDE + r] = f.y;
        wt[(cq + 2) * WT_STRIDE + r] = f.z;
        wt[(cq + 3) * WT_STRIDE + r] = f.w;
      }
      __syncthreads();
#pragma unroll
      for (int c = 0; c < 16; ++c) {
        float4 wa = *(const float4*)&wt[c * WT_STRIDE + rg * 8];
        float4 wb = *(const float4*)&wt[c * WT_STRIDE + rg * 8 + 4];
        int col = (kc << 4) + c;
#pragma unroll
        for (int j = 0; j < 4; ++j) {
          float xv = xs[(pg * 4 + j) * XS_STRIDE + col];
          acc[0][j] += wa.x * xv; acc[1][j] += wa.y * xv;
          acc[2][j] += wa.z * xv; acc[3][j] += wa.w * xv;
          acc[4][j] += wb.x * xv; acc[5][j] += wb.y * xv;
          acc[6][j] += wb.z * xv; acc[7][j] += wb.w * xv;
        }
      }
    }
    __syncthreads();
    // rows 0..127 are k (store exp(k)); rows 128..255 are v (store raw).
    if (rg < 16) {
#pragma unroll
      for (int i = 0; i < 8; ++i) {
        int row = rg * 8 + i;
#pragma unroll
        for (int j = 0; j < 4; ++j)
          ks[row * KV_STRIDE + pg * 4 + j] = expf(acc[i][j]);
      }
    } else {
#pragma unroll
      for (int i = 0; i < 8; ++i) {
        int row = (rg - 16) * 8 + i;
#pragma unroll
        for (int j = 0; j < 4; ++j)
          vs[row * KV_STRIDE + pg * 4 + j] = acc[i][j];
      }
    }
    __syncthreads();
    // S partial: thread -> (row r = t>>1, half = t&1), accumulate in register
    {
      int r = t >> 1, half = t & 1;
#pragma unroll
      for (int p = 0; p < 16; ++p) sacc += ks[r * KV_STRIDE + half * 16 + p];
    }
    // P partial: thread -> (h = t>>6, dk = (t>>1)&31, dv half = t&1)
    {
      int h = t >> 6, dk = (t >> 1) & 31, dvh = t & 1;
      float ek[32];
      const float* krow = &ks[(h * 32 + dk) * KV_STRIDE];
#pragma unroll
      for (int q = 0; q < 8; ++q) {
        float4 f = *(const float4*)&krow[q * 4];
        ek[q * 4 + 0] = f.x; ek[q * 4 + 1] = f.y;
        ek[q * 4 + 2] = f.z; ek[q * 4 + 3] = f.w;
      }
#pragma unroll
      for (int u = 0; u < 16; ++u) {
        int dv = dvh * 16 + u;
        const float* vrow = &vs[(h * 32 + dv) * KV_STRIDE];
        float p = 0.f;
#pragma unroll
        for (int q = 0; q < 8; ++q) {
          float4 f = *(const float4*)&vrow[q * 4];
          p += ek[q * 4 + 0] * f.x + ek[q * 4 + 1] * f.y +
               ek[q * 4 + 2] * f.z + ek[q * 4 + 3] * f.w;
        }
        pacc[u] += p;
      }
    }
  }

  // one write per value into slot (4 blocks share a slot -> low contention)
  {
    int r = t >> 1, half = t & 1;
    float s = sacc + __shfl_xor(sacc, 1);
    if (half == 0) atomicAdd(&Sp[(b * 32 + slot) * 128 + r], s);
  }
  {
    int h = t >> 6, dk = (t >> 1) & 31, dvh = t & 1;
    float* dst = &Pp[((size_t)(b * 32 + slot) << 12) + (h * 32 + dk) * 32 + dvh * 16];
#pragma unroll
    for (int u = 0; u < 16; ++u) atomicAdd(&dst[u], pacc[u]);
  }
}

// ---------------------------------------------------------------------------
// Reduction: sum 32 slots -> final S[b][128], P[b][4096]
// grid = 132, block = 256
// ---------------------------------------------------------------------------
__global__ void lin_attn_reduce(const float* __restrict__ Pp,
                                const float* __restrict__ Sp,
                                float* __restrict__ Pf, float* __restrict__ Sf)
{
  int idx = blockIdx.x * 256 + threadIdx.x;
  if (idx < B_ * 4096) {
    int b = idx >> 12;
    const float* src = Pp + ((size_t)(b * 32) << 12) + (idx & 4095);
    float s = 0.f;
#pragma unroll
    for (int k = 0; k < 32; ++k) s += src[(size_t)k << 12];
    Pf[idx] = s;
  } else {
    int j = idx - B_ * 4096;   // [0, 1024)
    int b = j >> 7;
    const float* src = Sp + (b * 32) * 128 + (j & 127);
    float s = 0.f;
#pragma unroll
    for (int k = 0; k < 32; ++k) s += src[k * 128];
    Sf[j] = s;
  }
}

// ---------------------------------------------------------------------------
// Kernel 2: q GEMM (rows 0..127 of w_qkv) -> per-pixel head softmax*scale ->
// attn = ctx^T q -> W_out GEMM + bias -> channel LayerNorm -> out.
// grid = B_ * 512, block = 256
// ---------------------------------------------------------------------------
__global__ __launch_bounds__(256, 2) void lin_attn_out(
    const float* __restrict__ x, const float* __restrict__ wqkv,
    const float* __restrict__ wout, const float* __restrict__ bout,
    const float* __restrict__ alpha, const float* __restrict__ beta,
    const float* __restrict__ Sg, const float* __restrict__ Pg,
    float* __restrict__ out)
{
  __shared__ __align__(16) float xs[32 * XS_STRIDE];  // x tile, later ctx[4][32][32]
  __shared__ __align__(16) float wt[16 * WT_STRIDE];
  __shared__ __align__(16) float qs[32 * QS_STRIDE];  // q tile, later y tile
  __shared__ __align__(16) float as_[32 * AS_STRIDE]; // attn tile
  __shared__ float red_s[256];
  __shared__ float red_q[256];

  const int t = threadIdx.x;
  const int b = blockIdx.x >> 9;
  const int p0 = (blockIdx.x & 511) << 5;

  // stage x tile
  {
    const float* xb = x + ((size_t)b * C_) * N_ + p0;
#pragma unroll
    for (int i = 0; i < 4; ++i) {
      int lin = t + 256 * i;
      int c = lin >> 3;
      int pq = (lin & 7) << 2;
      float4 f = *(const float4*)(xb + (size_t)c * N_ + pq);
      xs[(pq + 0) * XS_STRIDE + c] = f.x;
      xs[(pq + 1) * XS_STRIDE + c] = f.y;
      xs[(pq + 2) * XS_STRIDE + c] = f.z;
      xs[(pq + 3) * XS_STRIDE + c] = f.w;
    }
  }

  const int pg = t & 7;   // px = pg*4..pg*4+3
  const int rg = t >> 3;  // rows rg*4..rg*4+3 (128 rows)

  float acc[4][4];
#pragma unroll
  for (int i = 0; i < 4; ++i)
#pragma unroll
    for (int j = 0; j < 4; ++j) acc[i][j] = 0.f;

  // ---- q GEMM ----
  for (int kc = 0; kc < 8; ++kc) {
    __syncthreads();
#pragma unroll
    for (int i = 0; i < 2; ++i) {
      int lin = t + 256 * i;            // 512 float4s
      int r = lin >> 2;                 // 0..127
      int cq = (lin & 3) << 2;
      float4 f = *(const float4*)(wqkv + (size_t)r * C_ + (kc << 4) + cq);
      wt[(cq + 0) * WT_STRIDE + r] = f.x;
      wt[(cq + 1) * WT_STRIDE + r] = f.y;
      wt[(cq + 2) * WT_STRIDE + r] = f.z;
      wt[(cq + 3) * WT_STRIDE + r] = f.w;
    }
    __syncthreads();
#pragma unroll
    for (int c = 0; c < 16; ++c) {
      float4 wv = *(const float4*)&wt[c * WT_STRIDE + rg * 4];
      int col = (kc << 4) + c;
#pragma unroll
      for (int j = 0; j < 4; ++j) {
        float xv = xs[(pg * 4 + j) * XS_STRIDE + col];
        acc[0][j] += wv.x * xv; acc[1][j] += wv.y * xv;
        acc[2][j] += wv.z * xv; acc[3][j] += wv.w * xv;
      }
    }
  }
  // write q tile (pixel-major)
#pragma unroll
  for (int i = 0; i < 4; ++i)
#pragma unroll
    for (int j = 0; j < 4; ++j)
      qs[(pg * 4 + j) * QS_STRIDE + rg * 4 + i] = acc[i][j];
  __syncthreads();
  // stage normalized context into xs region: ctx = P / (S * n)
#pragma unroll
  for (int i = 0; i < 16; ++i) {
    int lin = t + 256 * i;              // 4096 entries: h*1024 + dk*32 + dv
    xs[lin] = Pg[b * 4096 + lin] / (Sg[b * 128 + (lin >> 5)] * 16384.f);
  }
  __syncthreads();
  // ---- per-pixel head softmax + attn matvec ----
  {
    int px = t & 31, h = (t >> 5) & 3, dvh = t >> 7;
    float qv[32];
#pragma unroll
    for (int q = 0; q < 8; ++q) {
      float4 f = *(const float4*)&qs[px * QS_STRIDE + h * 32 + q * 4];
      qv[q * 4 + 0] = f.x; qv[q * 4 + 1] = f.y;
      qv[q * 4 + 2] = f.z; qv[q * 4 + 3] = f.w;
    }
    float m = qv[0];
#pragma unroll
    for (int j = 1; j < 32; ++j) m = fmaxf(m, qv[j]);
    float s = 0.f;
#pragma unroll
    for (int j = 0; j < 32; ++j) { qv[j] = expf(qv[j] - m); s += qv[j]; }
    float inv = SCALE_ / s;
#pragma unroll
    for (int j = 0; j < 32; ++j) qv[j] *= inv;
    float av[16];
#pragma unroll
    for (int u = 0; u < 16; ++u) av[u] = 0.f;
#pragma unroll
    for (int dk = 0; dk < 32; ++dk) {
      float qk = qv[dk];
      const float* crow = &xs[h * 1024 + dk * 32 + dvh * 16];
#pragma unroll
      for (int u = 0; u < 4; ++u) {
        float4 f = *(const float4*)&crow[u * 4];
        av[u * 4 + 0] += qk * f.x; av[u * 4 + 1] += qk * f.y;
        av[u * 4 + 2] += qk * f.z; av[u * 4 + 3] += qk * f.w;
      }
    }
#pragma unroll
    for (int u = 0; u < 16; ++u)
      as_[px * AS_STRIDE + h * 32 + dvh * 16 + u] = av[u];
  }
  // ---- W_out GEMM ----
#pragma unroll
  for (int i = 0; i < 4; ++i)
#pragma unroll
    for (int j = 0; j < 4; ++j) acc[i][j] = 0.f;
  for (int kc = 0; kc < 8; ++kc) {
    __syncthreads();
#pragma unroll
    for (int i = 0; i < 2; ++i) {
      int lin = t + 256 * i;
      int r = lin >> 2;
      int cq = (lin & 3) << 2;
      float4 f = *(const float4*)(wout + (size_t)r * C_ + (kc << 4) + cq);
      wt[(cq + 0) * WT_STRIDE + r] = f.x;
      wt[(cq + 1) * WT_STRIDE + r] = f.y;
      wt[(cq + 2) * WT_STRIDE + r] = f.z;
      wt[(cq + 3) * WT_STRIDE + r] = f.w;
    }
    __syncthreads();
#pragma unroll
    for (int c = 0; c < 16; ++c) {
      float4 wv = *(const float4*)&wt[c * WT_STRIDE + rg * 4];
      int col = (kc << 4) + c;
#pragma unroll
      for (int j = 0; j < 4; ++j) {
        float xv = as_[(pg * 4 + j) * AS_STRIDE + col];
        acc[0][j] += wv.x * xv; acc[1][j] += wv.y * xv;
        acc[2][j] += wv.z * xv; acc[3][j] += wv.w * xv;
      }
    }
  }
  // bias + write y tile into qs region (q tile is dead)
  {
    float bias[4];
#pragma unroll
    for (int i = 0; i < 4; ++i) bias[i] = bout[rg * 4 + i];
#pragma unroll
    for (int i = 0; i < 4; ++i)
#pragma unroll
      for (int j = 0; j < 4; ++j)
        qs[(pg * 4 + j) * QS_STRIDE + rg * 4 + i] = acc[i][j] + bias[i];
  }
  __syncthreads();
  // ---- LayerNorm over 128 channels per pixel ----
  {
    int px = t & 31, cg = t >> 5;       // cg: 8 groups of 16 channels
    float y[16];
#pragma unroll
    for (int u = 0; u < 4; ++u) {
      float4 f = *(const float4*)&qs[px * QS_STRIDE + cg * 16 + u * 4];
      y[u * 4 + 0] = f.x; y[u * 4 + 1] = f.y;
      y[u * 4 + 2] = f.z; y[u * 4 + 3] = f.w;
    }
    float sm = 0.f, sq = 0.f;
#pragma unroll
    for (int u = 0; u < 16; ++u) { sm += y[u]; sq += y[u] * y[u]; }
    red_s[cg * 32 + px] = sm;
    red_q[cg * 32 + px] = sq;
    __syncthreads();
    float ts = 0.f, tq = 0.f;
#pragma unroll
    for (int g = 0; g < 8; ++g) { ts += red_s[g * 32 + px]; tq += red_q[g * 32 + px]; }
    float mean = ts * (1.f / 128.f);
    float var = tq * (1.f / 128.f) - mean * mean;
    float rstd = 1.f / sqrtf(var + EPS_);
    float* ob = out + ((size_t)b * C_) * N_ + p0 + px;
#pragma unroll
    for (int u = 0; u < 16; ++u) {
      int ch = cg * 16 + u;
      ob[(size_t)ch * N_] = (y[u] - mean) * rstd * alpha[ch] + beta[ch];
    }
  }
}

extern "C" void kernel_launch(void* const* d_in, const int* in_sizes, int n_in,
                              void* d_out, int out_size, void* d_ws, size_t ws_size,
                              hipStream_t stream) {
  const float* x     = (const float*)d_in[0];
  const float* wqkv  = (const float*)d_in[1];
  const float* wout  = (const float*)d_in[2];
  const float* bout  = (const float*)d_in[3];
  const float* alpha = (const float*)d_in[4];
  const float* beta  = (const float*)d_in[5];
  float* outp = (float*)d_out;

  float* Pp = (float*)d_ws;                      // [B][32][4096] partial P
  float* Sp = Pp + (size_t)B_ * 32 * 4096;       // [B][32][128]  partial S
  float* Pf = Sp + (size_t)B_ * 32 * 128;        // [B][4096]     final P
  float* Sf = Pf + (size_t)B_ * 4096;            // [B][128]      final S

  size_t partial_bytes = ((size_t)B_ * 32 * 4096 + (size_t)B_ * 32 * 128) * sizeof(float);
  hipMemsetAsync(d_ws, 0, partial_bytes, stream);

  lin_attn_ctx<<<dim3(B_ * 128), dim3(256), 0, stream>>>(x, wqkv, Sp, Pp);
  lin_attn_reduce<<<dim3(132), dim3(256), 0, stream>>>(Pp, Sp, Pf, Sf);
  lin_attn_out<<<dim3(B_ * 512), dim3(256), 0, stream>>>(x, wqkv, wout, bout,
                                                         alpha, beta, Sf, Pf, outp);
}

// Round 3
// 488.127 us; speedup vs baseline: 2.7133x; 1.2827x over previous
//
#include <hip/hip_runtime.h>
#include <math.h>

#define B_ 8
#define C_ 128
#define N_ 16384
#define SCALE_ 0.17677669529663687f
#define EPS_ 1e-5f

#define XS_STRIDE 133   // x / ctx tile, pixel-major [32][133]
#define WT_STRIDE 260   // w chunk, c-major [16][260]
#define KV_STRIDE 36    // k/v tiles [128][36]
#define QS_STRIDE 132   // q / y tile [32][132]
#define AS_STRIDE 133   // attn tile [32][133]

#define REC_ 4224       // per-block record: 4096 P + 128 S

// ---------------------------------------------------------------------------
// Kernel 1: k/v GEMM (rows 128..383 of w_qkv) over nchunks chunks of 32 px,
// exp(k), accumulate S/P partials in REGISTERS across chunks, then plain
// coalesced stores into a private per-block record (NO atomics).
// LDS overlay: {xs,wt} (GEMM phase) union {ks,vs} (P phase) -> 36.9 KB,
// 4 blocks/CU.
// grid = B_ * bpb, block = 256
// ---------------------------------------------------------------------------
__global__ __launch_bounds__(256, 4) void lin_attn_ctx(
    const float* __restrict__ x, const float* __restrict__ wqkv,
    float* __restrict__ Ws)
{
  __shared__ __align__(16) float smem[2 * 128 * KV_STRIDE];  // 9216 floats
  float* xs = smem;                       // [32][133] during GEMM (4256)
  float* wt = smem + 32 * XS_STRIDE;      // [16][260] during GEMM (4160)
  float* ks = smem;                       // [128][36] during P phase
  float* vs = smem + 128 * KV_STRIDE;     // [128][36]

  const int t = threadIdx.x;
  const int bpb = gridDim.x / B_;         // blocks per batch (pow2)
  const int b = blockIdx.x / bpb;
  const int blk = blockIdx.x - b * bpb;
  const int nchunks = 512 / bpb;
  const int pbase = blk * (nchunks << 5);

  const int pg = t & 7;   // pixel group: px = pg*4..pg*4+3
  const int rg = t >> 3;  // row group: rows rg*8..rg*8+7 (256 kv rows)

  float pacc[16];
#pragma unroll
  for (int u = 0; u < 16; ++u) pacc[u] = 0.f;
  float sacc = 0.f;

  for (int c4 = 0; c4 < nchunks; ++c4) {
    const int p0 = pbase + (c4 << 5);
    __syncthreads();   // previous P-phase reads done before xs overwrite
    // stage x tile [128 c][32 px] -> xs[px][c] (transposed, pixel-major)
    {
      const float* xb = x + ((size_t)b * C_) * N_ + p0;
#pragma unroll
      for (int i = 0; i < 4; ++i) {
        int lin = t + 256 * i;            // 1024 float4s
        int c = lin >> 3;
        int pq = (lin & 7) << 2;
        float4 f = *(const float4*)(xb + (size_t)c * N_ + pq);
        xs[(pq + 0) * XS_STRIDE + c] = f.x;
        xs[(pq + 1) * XS_STRIDE + c] = f.y;
        xs[(pq + 2) * XS_STRIDE + c] = f.z;
        xs[(pq + 3) * XS_STRIDE + c] = f.w;
      }
    }

    float acc[8][4];
#pragma unroll
    for (int i = 0; i < 8; ++i)
#pragma unroll
      for (int j = 0; j < 4; ++j) acc[i][j] = 0.f;

    for (int kc = 0; kc < 8; ++kc) {
      __syncthreads();
      // stage w chunk: rows 128..383, cols kc*16..+15  ->  wt[cc][r]
#pragma unroll
      for (int i = 0; i < 4; ++i) {
        int lin = t + 256 * i;            // 1024 float4s
        int r = lin >> 2;                 // 0..255
        int cq = (lin & 3) << 2;
        float4 f = *(const float4*)(wqkv + (size_t)(128 + r) * C_ + (kc << 4) + cq);
        wt[(cq + 0) * WT_STRIDE + r] = f.x;
        wt[(cq + 1) * WT_STRIDE + r] = f.y;
        wt[(cq + 2) * WT_STRIDE + r] = f.z;
        wt[(cq + 3) * WT_STRIDE + r] = f.w;
      }
      __syncthreads();
#pragma unroll
      for (int c = 0; c < 16; ++c) {
        float4 wa = *(const float4*)&wt[c * WT_STRIDE + rg * 8];
        float4 wb = *(const float4*)&wt[c * WT_STRIDE + rg * 8 + 4];
        int col = (kc << 4) + c;
#pragma unroll
        for (int j = 0; j < 4; ++j) {
          float xv = xs[(pg * 4 + j) * XS_STRIDE + col];
          acc[0][j] += wa.x * xv; acc[1][j] += wa.y * xv;
          acc[2][j] += wa.z * xv; acc[3][j] += wa.w * xv;
          acc[4][j] += wb.x * xv; acc[5][j] += wb.y * xv;
          acc[6][j] += wb.z * xv; acc[7][j] += wb.w * xv;
        }
      }
    }
    __syncthreads();   // GEMM reads of xs/wt done before ks/vs overwrite
    // rows 0..127 are k (store exp(k)); rows 128..255 are v (store raw).
    if (rg < 16) {
#pragma unroll
      for (int i = 0; i < 8; ++i) {
        int row = rg * 8 + i;
#pragma unroll
        for (int j = 0; j < 4; ++j)
          ks[row * KV_STRIDE + pg * 4 + j] = expf(acc[i][j]);
      }
    } else {
#pragma unroll
      for (int i = 0; i < 8; ++i) {
        int row = (rg - 16) * 8 + i;
#pragma unroll
        for (int j = 0; j < 4; ++j)
          vs[row * KV_STRIDE + pg * 4 + j] = acc[i][j];
      }
    }
    __syncthreads();
    // S partial: thread -> (row r = t>>1, half = t&1), accumulate in register
    {
      int r = t >> 1, half = t & 1;
#pragma unroll
      for (int p = 0; p < 16; ++p) sacc += ks[r * KV_STRIDE + half * 16 + p];
    }
    // P partial: thread -> (h = t>>6, dk = (t>>1)&31, dv half = t&1)
    {
      int h = t >> 6, dk = (t >> 1) & 31, dvh = t & 1;
      float ek[32];
      const float* krow = &ks[(h * 32 + dk) * KV_STRIDE];
#pragma unroll
      for (int q = 0; q < 8; ++q) {
        float4 f = *(const float4*)&krow[q * 4];
        ek[q * 4 + 0] = f.x; ek[q * 4 + 1] = f.y;
        ek[q * 4 + 2] = f.z; ek[q * 4 + 3] = f.w;
      }
#pragma unroll
      for (int u = 0; u < 16; ++u) {
        int dv = dvh * 16 + u;
        const float* vrow = &vs[(h * 32 + dv) * KV_STRIDE];
        float p = 0.f;
#pragma unroll
        for (int q = 0; q < 8; ++q) {
          float4 f = *(const float4*)&vrow[q * 4];
          p += ek[q * 4 + 0] * f.x + ek[q * 4 + 1] * f.y +
               ek[q * 4 + 2] * f.z + ek[q * 4 + 3] * f.w;
        }
        pacc[u] += p;
      }
    }
  }

  // plain coalesced stores into private record (no atomics)
  {
    float* rec = Ws + (size_t)blockIdx.x * REC_;
    int h = t >> 6, dk = (t >> 1) & 31, dvh = t & 1;
    float* dst = &rec[(h * 32 + dk) * 32 + dvh * 16];
#pragma unroll
    for (int q = 0; q < 4; ++q) {
      float4 f;
      f.x = pacc[q * 4 + 0]; f.y = pacc[q * 4 + 1];
      f.z = pacc[q * 4 + 2]; f.w = pacc[q * 4 + 3];
      *(float4*)&dst[q * 4] = f;
    }
    int r = t >> 1, half = t & 1;
    float s = sacc + __shfl_xor(sacc, 1);
    if (half == 0) rec[4096 + r] = s;
  }
}

// ---------------------------------------------------------------------------
// Reduction: sum `slots` records per batch -> final P[b][4096], S[b][128]
// grid = 132, block = 256  (8 * 4224 = 33792 outputs)
// ---------------------------------------------------------------------------
__global__ void lin_attn_reduce(const float* __restrict__ Ws, int slots,
                                float* __restrict__ Pf, float* __restrict__ Sf)
{
  int idx = blockIdx.x * 256 + threadIdx.x;
  int b = idx / REC_;
  int j = idx - b * REC_;
  const float* src = Ws + (size_t)b * slots * REC_ + j;
  float s0 = 0.f, s1 = 0.f, s2 = 0.f, s3 = 0.f;
  for (int k = 0; k < slots; k += 4) {
    s0 += src[(size_t)(k + 0) * REC_];
    s1 += src[(size_t)(k + 1) * REC_];
    s2 += src[(size_t)(k + 2) * REC_];
    s3 += src[(size_t)(k + 3) * REC_];
  }
  float s = (s0 + s1) + (s2 + s3);
  if (j < 4096) Pf[b * 4096 + j] = s;
  else          Sf[b * 128 + (j - 4096)] = s;
}

// ---------------------------------------------------------------------------
// Kernel 2: q GEMM (rows 0..127 of w_qkv) -> per-pixel head softmax*scale ->
// attn = ctx^T q -> W_out GEMM + bias -> channel LayerNorm -> out.
// grid = B_ * 512, block = 256
// ---------------------------------------------------------------------------
__global__ __launch_bounds__(256, 2) void lin_attn_out(
    const float* __restrict__ x, const float* __restrict__ wqkv,
    const float* __restrict__ wout, const float* __restrict__ bout,
    const float* __restrict__ alpha, const float* __restrict__ beta,
    const float* __restrict__ Sg, const float* __restrict__ Pg,
    float* __restrict__ out)
{
  __shared__ __align__(16) float xs[32 * XS_STRIDE];  // x tile, later ctx[4][32][32]
  __shared__ __align__(16) float wt[16 * WT_STRIDE];
  __shared__ __align__(16) float qs[32 * QS_STRIDE];  // q tile, later y tile
  __shared__ __align__(16) float as_[32 * AS_STRIDE]; // attn tile
  __shared__ float red_s[256];
  __shared__ float red_q[256];

  const int t = threadIdx.x;
  const int b = blockIdx.x >> 9;
  const int p0 = (blockIdx.x & 511) << 5;

  // stage x tile
  {
    const float* xb = x + ((size_t)b * C_) * N_ + p0;
#pragma unroll
    for (int i = 0; i < 4; ++i) {
      int lin = t + 256 * i;
      int c = lin >> 3;
      int pq = (lin & 7) << 2;
      float4 f = *(const float4*)(xb + (size_t)c * N_ + pq);
      xs[(pq + 0) * XS_STRIDE + c] = f.x;
      xs[(pq + 1) * XS_STRIDE + c] = f.y;
      xs[(pq + 2) * XS_STRIDE + c] = f.z;
      xs[(pq + 3) * XS_STRIDE + c] = f.w;
    }
  }

  const int pg = t & 7;   // px = pg*4..pg*4+3
  const int rg = t >> 3;  // rows rg*4..rg*4+3 (128 rows)

  float acc[4][4];
#pragma unroll
  for (int i = 0; i < 4; ++i)
#pragma unroll
    for (int j = 0; j < 4; ++j) acc[i][j] = 0.f;

  // ---- q GEMM ----
  for (int kc = 0; kc < 8; ++kc) {
    __syncthreads();
#pragma unroll
    for (int i = 0; i < 2; ++i) {
      int lin = t + 256 * i;            // 512 float4s
      int r = lin >> 2;                 // 0..127
      int cq = (lin & 3) << 2;
      float4 f = *(const float4*)(wqkv + (size_t)r * C_ + (kc << 4) + cq);
      wt[(cq + 0) * WT_STRIDE + r] = f.x;
      wt[(cq + 1) * WT_STRIDE + r] = f.y;
      wt[(cq + 2) * WT_STRIDE + r] = f.z;
      wt[(cq + 3) * WT_STRIDE + r] = f.w;
    }
    __syncthreads();
#pragma unroll
    for (int c = 0; c < 16; ++c) {
      float4 wv = *(const float4*)&wt[c * WT_STRIDE + rg * 4];
      int col = (kc << 4) + c;
#pragma unroll
      for (int j = 0; j < 4; ++j) {
        float xv = xs[(pg * 4 + j) * XS_STRIDE + col];
        acc[0][j] += wv.x * xv; acc[1][j] += wv.y * xv;
        acc[2][j] += wv.z * xv; acc[3][j] += wv.w * xv;
      }
    }
  }
  // write q tile (pixel-major)
#pragma unroll
  for (int i = 0; i < 4; ++i)
#pragma unroll
    for (int j = 0; j < 4; ++j)
      qs[(pg * 4 + j) * QS_STRIDE + rg * 4 + i] = acc[i][j];
  __syncthreads();
  // stage normalized context into xs region: ctx = P / (S * n)
#pragma unroll
  for (int i = 0; i < 16; ++i) {
    int lin = t + 256 * i;              // 4096 entries: h*1024 + dk*32 + dv
    xs[lin] = Pg[b * 4096 + lin] / (Sg[b * 128 + (lin >> 5)] * 16384.f);
  }
  __syncthreads();
  // ---- per-pixel head softmax + attn matvec ----
  {
    int px = t & 31, h = (t >> 5) & 3, dvh = t >> 7;
    float qv[32];
#pragma unroll
    for (int q = 0; q < 8; ++q) {
      float4 f = *(const float4*)&qs[px * QS_STRIDE + h * 32 + q * 4];
      qv[q * 4 + 0] = f.x; qv[q * 4 + 1] = f.y;
      qv[q * 4 + 2] = f.z; qv[q * 4 + 3] = f.w;
    }
    float m = qv[0];
#pragma unroll
    for (int j = 1; j < 32; ++j) m = fmaxf(m, qv[j]);
    float s = 0.f;
#pragma unroll
    for (int j = 0; j < 32; ++j) { qv[j] = expf(qv[j] - m); s += qv[j]; }
    float inv = SCALE_ / s;
#pragma unroll
    for (int j = 0; j < 32; ++j) qv[j] *= inv;
    float av[16];
#pragma unroll
    for (int u = 0; u < 16; ++u) av[u] = 0.f;
#pragma unroll
    for (int dk = 0; dk < 32; ++dk) {
      float qk = qv[dk];
      const float* crow = &xs[h * 1024 + dk * 32 + dvh * 16];
#pragma unroll
      for (int u = 0; u < 4; ++u) {
        float4 f = *(const float4*)&crow[u * 4];
        av[u * 4 + 0] += qk * f.x; av[u * 4 + 1] += qk * f.y;
        av[u * 4 + 2] += qk * f.z; av[u * 4 + 3] += qk * f.w;
      }
    }
#pragma unroll
    for (int u = 0; u < 16; ++u)
      as_[px * AS_STRIDE + h * 32 + dvh * 16 + u] = av[u];
  }
  // ---- W_out GEMM ----
#pragma unroll
  for (int i = 0; i < 4; ++i)
#pragma unroll
    for (int j = 0; j < 4; ++j) acc[i][j] = 0.f;
  for (int kc = 0; kc < 8; ++kc) {
    __syncthreads();
#pragma unroll
    for (int i = 0; i < 2; ++i) {
      int lin = t + 256 * i;
      int r = lin >> 2;
      int cq = (lin & 3) << 2;
      float4 f = *(const float4*)(wout + (size_t)r * C_ + (kc << 4) + cq);
      wt[(cq + 0) * WT_STRIDE + r] = f.x;
      wt[(cq + 1) * WT_STRIDE + r] = f.y;
      wt[(cq + 2) * WT_STRIDE + r] = f.z;
      wt[(cq + 3) * WT_STRIDE + r] = f.w;
    }
    __syncthreads();
#pragma unroll
    for (int c = 0; c < 16; ++c) {
      float4 wv = *(const float4*)&wt[c * WT_STRIDE + rg * 4];
      int col = (kc << 4) + c;
#pragma unroll
      for (int j = 0; j < 4; ++j) {
        float xv = as_[(pg * 4 + j) * AS_STRIDE + col];
        acc[0][j] += wv.x * xv; acc[1][j] += wv.y * xv;
        acc[2][j] += wv.z * xv; acc[3][j] += wv.w * xv;
      }
    }
  }
  // bias + write y tile into qs region (q tile is dead)
  {
    float bias[4];
#pragma unroll
    for (int i = 0; i < 4; ++i) bias[i] = bout[rg * 4 + i];
#pragma unroll
    for (int i = 0; i < 4; ++i)
#pragma unroll
      for (int j = 0; j < 4; ++j)
        qs[(pg * 4 + j) * QS_STRIDE + rg * 4 + i] = acc[i][j] + bias[i];
  }
  __syncthreads();
  // ---- LayerNorm over 128 channels per pixel ----
  {
    int px = t & 31, cg = t >> 5;       // cg: 8 groups of 16 channels
    float y[16];
#pragma unroll
    for (int u = 0; u < 4; ++u) {
      float4 f = *(const float4*)&qs[px * QS_STRIDE + cg * 16 + u * 4];
      y[u * 4 + 0] = f.x; y[u * 4 + 1] = f.y;
      y[u * 4 + 2] = f.z; y[u * 4 + 3] = f.w;
    }
    float sm = 0.f, sq = 0.f;
#pragma unroll
    for (int u = 0; u < 16; ++u) { sm += y[u]; sq += y[u] * y[u]; }
    red_s[cg * 32 + px] = sm;
    red_q[cg * 32 + px] = sq;
    __syncthreads();
    float ts = 0.f, tq = 0.f;
#pragma unroll
    for (int g = 0; g < 8; ++g) { ts += red_s[g * 32 + px]; tq += red_q[g * 32 + px]; }
    float mean = ts * (1.f / 128.f);
    float var = tq * (1.f / 128.f) - mean * mean;
    float rstd = 1.f / sqrtf(var + EPS_);
    float* ob = out + ((size_t)b * C_) * N_ + p0 + px;
#pragma unroll
    for (int u = 0; u < 16; ++u) {
      int ch = cg * 16 + u;
      ob[(size_t)ch * N_] = (y[u] - mean) * rstd * alpha[ch] + beta[ch];
    }
  }
}

extern "C" void kernel_launch(void* const* d_in, const int* in_sizes, int n_in,
                              void* d_out, int out_size, void* d_ws, size_t ws_size,
                              hipStream_t stream) {
  const float* x     = (const float*)d_in[0];
  const float* wqkv  = (const float*)d_in[1];
  const float* wout  = (const float*)d_in[2];
  const float* bout  = (const float*)d_in[3];
  const float* alpha = (const float*)d_in[4];
  const float* beta  = (const float*)d_in[5];
  float* outp = (float*)d_out;

  // pick slots/batch by workspace size (deterministic -> graph-safe)
  size_t need128 = ((size_t)B_ * 128 * REC_ + B_ * 4096 + B_ * 128) * sizeof(float);
  int bpb = (ws_size >= need128) ? 128 : 32;

  float* Ws = (float*)d_ws;                          // [B*bpb][4224] records
  float* Pf = Ws + (size_t)B_ * bpb * REC_;          // [B][4096]
  float* Sf = Pf + (size_t)B_ * 4096;                // [B][128]

  lin_attn_ctx<<<dim3(B_ * bpb), dim3(256), 0, stream>>>(x, wqkv, Ws);
  lin_attn_reduce<<<dim3(132), dim3(256), 0, stream>>>(Ws, bpb, Pf, Sf);
  lin_attn_out<<<dim3(B_ * 512), dim3(256), 0, stream>>>(x, wqkv, wout, bout,
                                                         alpha, beta, Sf, Pf, outp);
}